// Round 9
// baseline (3044.481 us; speedup 1.0000x reference)
//
#include <hip/hip_runtime.h>
#include <hip/hip_bf16.h>

typedef __bf16 bf8 __attribute__((ext_vector_type(8)));   // 16 B
typedef float  f32x4 __attribute__((ext_vector_type(4)));
typedef unsigned long long u64;

#define TT 512
#define BBATCH 64
#define IDIM 1024
#define HDIM 1024
#define G4 4096
#define NREC 128

__device__ __forceinline__ float sigf(float x) {
  x = fminf(fmaxf(x, -30.f), 30.f);
  return 1.f / (1.f + __expf(-x));
}
__device__ __forceinline__ float tanh_(float x) {
  x = fminf(fmaxf(x, -15.f), 15.f);
  float e = __expf(2.f * x);
  return (e - 1.f) / (e + 1.f);
}
__device__ __forceinline__ f32x4 MFMA(bf8 a, bf8 b, f32x4 c) {
  return __builtin_amdgcn_mfma_f32_16x16x32_bf16(a, b, c, 0, 0, 0);
}

// ---------------------------------------------------------------------------
// Weight transpose+convert via LDS tiles (plain [n][k] bf16 for BOTH Wx, Wh).
// ---------------------------------------------------------------------------
__global__ __launch_bounds__(256) void k_convw(
    const float* __restrict__ s0, const float* __restrict__ s1,
    const float* __restrict__ s2, const float* __restrict__ s3,
    const float* __restrict__ s4, const float* __restrict__ s5,
    const float* __restrict__ s6, const float* __restrict__ s7,
    __bf16* __restrict__ WxT, __bf16* __restrict__ WhT) {
  int z = blockIdx.z;
  const float* src = (z == 0) ? s0 : (z == 1) ? s1 : (z == 2) ? s2 :
                     (z == 3) ? s3 : (z == 4) ? s4 : (z == 5) ? s5 :
                     (z == 6) ? s6 : s7;
  __bf16* dst = (z < 4) ? WxT : WhT;
  int j0 = blockIdx.x * 64, k0 = blockIdx.y * 64;
  __shared__ float T[64][65];
  int tid = threadIdx.x;
#pragma unroll
  for (int i = 0; i < 16; ++i) {
    int idx = tid + i * 256;
    int kl = idx >> 6, jl = idx & 63;
    T[kl][jl] = src[(size_t)(k0 + kl) * 1024 + j0 + jl];
  }
  __syncthreads();
#pragma unroll
  for (int i = 0; i < 2; ++i) {
    int Gt = tid + i * 256;
    int nl = Gt >> 3, gq = Gt & 7;
    int n = (z & 3) * 1024 + j0 + nl;
    bf8 v;
#pragma unroll
    for (int e = 0; e < 8; ++e) v[e] = (__bf16)T[gq * 8 + e][nl];
    *(bf8*)&dst[(size_t)n * 1024 + k0 + gq * 8] = v;
  }
}

__global__ void k_bias(const float* __restrict__ b0, const float* __restrict__ b1,
                       const float* __restrict__ b2, const float* __restrict__ b3,
                       float* __restrict__ bias) {
  int i = blockIdx.x * 256 + threadIdx.x;
  if (i < G4) {
    const float* s = (i < 1024) ? b0 : (i < 2048) ? b1 : (i < 3072) ? b2 : b3;
    bias[i] = s[i & 1023];
  }
}

// ---------------------------------------------------------------------------
// Fused persistent kernel. grid = 256 x 512 threads.
//  blocks [0, nrec):    recurrence for chunk starting at t0 (Tc steps)
//  blocks [nrec, 256):  GEMM Xg_w = Xnext @ WxT^T + bias (next chunk's gates)
//
// Recurrence block bid: rh = bid&1 (batch rows rh*32..+32), hc0=(bid>>1)*16.
// Wave w = kq (K slice of 128). Bf[4 gates][4 s] = 64 VGPR register-resident.
// A-frags loaded DIRECTLY from global h (agent u64, dup-free) -- h never
// touches LDS. LDS only for partial exchange: Gs[8][64][32] XOR-swizzled.
// Sync (PROVEN round 4-7): per-block int flag, all-wave poll v >= t,
// end-of-step __syncthreads (drains vmcnt + protects Gs reuse) + tid0 release.
// ---------------------------------------------------------------------------
__global__ __launch_bounds__(512, 1) void k_fused(
    const float* __restrict__ Xg_r, float* __restrict__ Xg_w,
    const __bf16* __restrict__ WhT, const __bf16* __restrict__ WxT,
    const float* __restrict__ Xnext, const float* __restrict__ bias,
    __bf16* __restrict__ hb0, __bf16* __restrict__ hb1,
    float* __restrict__ S, float* __restrict__ out,
    int* flags, int t0, int Tc, int nrec, int gM) {
  __shared__ char smem[65536];
  const int bid = blockIdx.x, tid = threadIdx.x;
  const int lane = tid & 63, w = tid >> 6;

  if (bid < nrec) {
    // =================== recurrence ===================
    float* Gsf = (float*)smem;               // Gs[8][64][32] f32, XOR-swizzled
    const int kq = w;
    const int rh = bid & 1, hc0 = (bid >> 1) * 16;
    const int l15 = lane & 15, lq = lane >> 4;
    const int rowbase = rh * 32;

    // ---- Wh fragments: Bf[g][s]: ncol = g*1024+hc0+l15, k = kq*128+s*32+lq*8
    bf8 Bf[16];
#pragma unroll
    for (int g = 0; g < 4; ++g)
#pragma unroll
      for (int s = 0; s < 4; ++s)
        Bf[g * 4 + s] = *(const bf8*)&WhT[(size_t)(g * 1024 + hc0 + l15) * 1024 +
                                          kq * 128 + s * 32 + lq * 8];
#pragma unroll
    for (int i = 0; i < 16; ++i) {
      float4 tp = __builtin_bit_cast(float4, Bf[i]);
      asm volatile("" : "+v"(tp.x), "+v"(tp.y), "+v"(tp.z), "+v"(tp.w));
      Bf[i] = __builtin_bit_cast(bf8, tp);
    }

    // ---- gate-phase mapping: 1 (batch,col) per thread ----
    const int er = tid >> 4, ec = tid & 15;
    float sreg = 0.f;
    if (t0 > 0) sreg = S[(size_t)(rowbase + er) * 1024 + hc0 + ec];

    for (int lt = 0; lt < Tc; ++lt) {
      const int t = t0 + lt;

      // Xg prefetch (independent of h, overlaps poll)
      const float* xp = Xg_r + ((size_t)lt * 64 + rowbase + er) * G4 + hc0 + ec;
      float xa = xp[0], xi = xp[1024], xf = xp[2048], xo = xp[3072];

      if (t > 0) {
        if (lt > 0) {
          // poll same-rh producers: monotone >= (skew-tolerant, PROVEN)
          int v;
          do {
            v = __hip_atomic_load(flags + (2 * lane + rh) * 32, __ATOMIC_RELAXED,
                                  __HIP_MEMORY_SCOPE_AGENT);
          } while (!__all(v >= t));
          asm volatile("" ::: "memory");   // no hoisting h-loads above poll
        }
        const __bf16* hp = ((t - 1) & 1) ? hb1 : hb0;

        // A-frags direct from global (dup-free: wave kq owns K slice 128)
        u64 aq[16];
#pragma unroll
        for (int mh = 0; mh < 2; ++mh) {
          const __bf16* hr = hp + (size_t)(rowbase + mh * 16 + l15) * 1024 +
                             kq * 128 + lq * 8;
#pragma unroll
          for (int s = 0; s < 4; ++s) {
            const u64* p = (const u64*)(hr + s * 32);
            aq[(mh * 4 + s) * 2 + 0] = __hip_atomic_load(p, __ATOMIC_RELAXED,
                                                         __HIP_MEMORY_SCOPE_AGENT);
            aq[(mh * 4 + s) * 2 + 1] = __hip_atomic_load(p + 1, __ATOMIC_RELAXED,
                                                         __HIP_MEMORY_SCOPE_AGENT);
          }
        }

        f32x4 acc[2][4] = {};
#pragma unroll
        for (int s = 0; s < 4; ++s)
#pragma unroll
          for (int mh = 0; mh < 2; ++mh) {
            union { u64 q[2]; bf8 v; } u;
            u.q[0] = aq[(mh * 4 + s) * 2 + 0];
            u.q[1] = aq[(mh * 4 + s) * 2 + 1];
            acc[mh][0] = MFMA(u.v, Bf[0 * 4 + s], acc[mh][0]);
            acc[mh][1] = MFMA(u.v, Bf[1 * 4 + s], acc[mh][1]);
            acc[mh][2] = MFMA(u.v, Bf[2 * 4 + s], acc[mh][2]);
            acc[mh][3] = MFMA(u.v, Bf[3 * 4 + s], acc[mh][3]);
          }

        // transposed partial write: Gs[kq][col = g*16+l15][row], XOR-swizzled
#pragma unroll
        for (int mh = 0; mh < 2; ++mh)
#pragma unroll
          for (int g = 0; g < 4; ++g)
            *(f32x4*)&Gsf[(size_t)((kq * 64 + g * 16 + l15) * 32 +
                                   ((mh * 16 + lq * 4) ^ ((l15 & 7) << 2)))] =
                acc[mh][g];
      }
      __syncthreads();

      if (t > 0) {
        // two-level reduce: thread owns (ncl = tid>>3, r4 = (tid&7)*4)
        const int ncl = tid >> 3;
        const int r4 = ((tid & 7) * 4) ^ ((ncl & 7) << 2);
        f32x4 sum = *(const f32x4*)&Gsf[(size_t)(ncl * 32 + r4)];
#pragma unroll
        for (int k2 = 1; k2 < 8; ++k2)
          sum += *(const f32x4*)&Gsf[(size_t)((k2 * 64 + ncl) * 32 + r4)];
        *(f32x4*)&Gsf[(size_t)(ncl * 32 + r4)] = sum;
      }
      __syncthreads();

      if (t > 0) {
        const int key = (ec & 7) << 2;
        xa += Gsf[(0 * 16 + ec) * 32 + (er ^ key)];
        xi += Gsf[(1 * 16 + ec) * 32 + (er ^ key)];
        xf += Gsf[(2 * 16 + ec) * 32 + (er ^ key)];
        xo += Gsf[(3 * 16 + ec) * 32 + (er ^ key)];
      }

      // ---- gates + state update ----
      float av = tanh_(xa), iv = sigf(xi), fv = sigf(xf), ov = sigf(xo);
      sreg = av * iv + sreg * fv;
      float h0 = tanh_(sreg) * ov;

      out[((size_t)t * 64 + rowbase + er) * 1024 + hc0 + ec] = h0;

      float hnb = __shfl(h0, lane + 1);
      if ((ec & 1) == 0) {
        unsigned int pv =
            (unsigned int)__builtin_bit_cast(unsigned short, (__bf16)h0) |
            ((unsigned int)__builtin_bit_cast(unsigned short, (__bf16)hnb) << 16);
        __bf16* hn = (t & 1) ? hb1 : hb0;
        __hip_atomic_store(
            (unsigned int*)((char*)hn + ((size_t)(rowbase + er) * 1024 + hc0 + ec) * 2),
            pv, __ATOMIC_RELAXED, __HIP_MEMORY_SCOPE_AGENT);
      }

      __syncthreads();   // drains vmcnt(0): all h stores at LLC; Gs reuse safe
      if (tid == 0)
        __hip_atomic_store(flags + bid * 32, t + 1, __ATOMIC_RELAXED,
                           __HIP_MEMORY_SCOPE_AGENT);
    }

    S[(size_t)(rowbase + er) * 1024 + hc0 + ec] = sreg;
    return;
  }

  // =================== worker GEMM (next chunk's Xg) ===================
  if (gM == 0) return;
  const int nw = gridDim.x - nrec;
  const int wid = bid - nrec;
  __bf16 (*As)[40] = (__bf16(*)[40])smem;
  __bf16 (*Bs)[40] = (__bf16(*)[40])(smem + 128 * 40 * 2);
  const int wr = (w >> 2) * 64, wc = (w & 3) * 32;
  const int sm = tid >> 2, sk = (tid & 3) * 8;
  const int gl15 = lane & 15, glq = lane >> 4;
  const int ntiles = (gM / 128) * (G4 / 128);

  for (int tile = wid; tile < ntiles; tile += nw) {
    const int m0 = (tile >> 5) * 128, n0 = (tile & 31) * 128;
    const float*  Ap = Xnext + (size_t)(m0 + sm) * 1024 + sk;
    const __bf16* Bp = WxT + (size_t)(n0 + sm) * 1024 + sk;
    f32x4 acc[4][2] = {};
    float4 ra0, ra1;
    bf8 rb;
    auto ld = [&](int kt) {
      ra0 = *(const float4*)(Ap + kt * 32);
      ra1 = *(const float4*)(Ap + kt * 32 + 4);
      rb = *(const bf8*)(Bp + kt * 32);
    };
    ld(0);
    for (int kt = 0; kt < 32; ++kt) {
      __syncthreads();
      bf8 va;
      va[0]=(__bf16)ra0.x; va[1]=(__bf16)ra0.y; va[2]=(__bf16)ra0.z; va[3]=(__bf16)ra0.w;
      va[4]=(__bf16)ra1.x; va[5]=(__bf16)ra1.y; va[6]=(__bf16)ra1.z; va[7]=(__bf16)ra1.w;
      *(bf8*)&As[sm][sk] = va;
      *(bf8*)&Bs[sm][sk] = rb;
      if (kt < 31) ld(kt + 1);
      __syncthreads();
      bf8 af[4], bv[2];
#pragma unroll
      for (int r = 0; r < 4; ++r) af[r] = *(const bf8*)&As[wr + r * 16 + gl15][glq * 8];
#pragma unroll
      for (int c = 0; c < 2; ++c) bv[c] = *(const bf8*)&Bs[wc + c * 16 + gl15][glq * 8];
#pragma unroll
      for (int r = 0; r < 4; ++r)
#pragma unroll
        for (int c = 0; c < 2; ++c)
          acc[r][c] = MFMA(af[r], bv[c], acc[r][c]);
    }
#pragma unroll
    for (int c = 0; c < 2; ++c) {
      int col = n0 + wc + c * 16 + gl15;
      float bc = bias[col];
#pragma unroll
      for (int r = 0; r < 4; ++r)
#pragma unroll
        for (int q = 0; q < 4; ++q)
          Xg_w[(size_t)(m0 + wr + r * 16 + glq * 4 + q) * G4 + col] = acc[r][c][q] + bc;
    }
    __syncthreads();
  }
}

// ---------------------------------------------------------------------------
extern "C" void kernel_launch(void* const* d_in, const int* in_sizes, int n_in,
                              void* d_out, int out_size, void* d_ws, size_t ws_size,
                              hipStream_t stream) {
  const float* X  = (const float*)d_in[0];
  const float* wa = (const float*)d_in[1];
  const float* wi = (const float*)d_in[2];
  const float* wf = (const float*)d_in[3];
  const float* wo = (const float*)d_in[4];
  const float* ha = (const float*)d_in[5];
  const float* hi = (const float*)d_in[6];
  const float* hf = (const float*)d_in[7];
  const float* ho = (const float*)d_in[8];
  const float* b0 = (const float*)d_in[9];
  const float* b1 = (const float*)d_in[10];
  const float* b2 = (const float*)d_in[11];
  const float* b3 = (const float*)d_in[12];
  float* out = (float*)d_out;
  char* ws = (char*)d_ws;

  size_t off = 0;
  auto alloc = [&](size_t bytes) {
    void* p = ws + off;
    off += (bytes + 255) & ~(size_t)255;
    return p;
  };
  __bf16* WxT = (__bf16*)alloc((size_t)G4 * IDIM * 2);
  __bf16* WhT = (__bf16*)alloc((size_t)G4 * HDIM * 2);
  float* bias = (float*)alloc(G4 * 4);
  float* S    = (float*)alloc((size_t)BBATCH * HDIM * 4);
  __bf16* hb0 = (__bf16*)alloc((size_t)BBATCH * HDIM * 2);
  __bf16* hb1 = (__bf16*)alloc((size_t)BBATCH * HDIM * 2);
  int* flags  = (int*)alloc(NREC * 32 * 4);
  size_t base = off;

  const size_t perXg = (size_t)BBATCH * G4 * 4;  // 1 MB per timestep
  int Tc = 64;
  while (Tc > 4 && base + 2 * (size_t)Tc * perXg > ws_size) Tc >>= 1;
  float* Xg0 = (float*)(ws + base);
  float* Xg1 = (float*)(ws + base + (size_t)Tc * perXg);
  int nchunks = TT / Tc;

  k_convw<<<dim3(16, 16, 8), dim3(256), 0, stream>>>(wa, wi, wf, wo, ha, hi, hf,
                                                     ho, WxT, WhT);
  k_bias<<<dim3(16), dim3(256), 0, stream>>>(b0, b1, b2, b3, bias);
  hipMemsetAsync(flags, 0, NREC * 32 * 4, stream);

  // prologue: all 256 blocks compute chunk 0's Xg
  k_fused<<<dim3(256), dim3(512), 0, stream>>>(
      nullptr, Xg0, WhT, WxT, X, bias, hb0, hb1, S, out, flags,
      0, 0, /*nrec=*/0, /*gM=*/Tc * BBATCH);

  for (int c = 0; c < nchunks; ++c) {
    float* xr = (c & 1) ? Xg1 : Xg0;
    float* xw = (c & 1) ? Xg0 : Xg1;
    int gM = (c + 1 < nchunks) ? Tc * BBATCH : 0;
    const float* Xn = X + (size_t)(c + 1) * Tc * BBATCH * IDIM;
    k_fused<<<dim3(256), dim3(512), 0, stream>>>(
        xr, xw, WhT, WxT, Xn, bias, hb0, hb1, S, out, flags,
        c * Tc, Tc, /*nrec=*/NREC, gM);
  }
}

// Round 10
// 2108.808 us; speedup vs baseline: 1.4437x; 1.4437x over previous
//
#include <hip/hip_runtime.h>
#include <hip/hip_bf16.h>

typedef __bf16 bf8 __attribute__((ext_vector_type(8)));   // 16 B
typedef float  f32x4  __attribute__((ext_vector_type(4)));
typedef float  f32x16 __attribute__((ext_vector_type(16)));
typedef unsigned long long u64;

#define TT 512
#define BBATCH 64
#define IDIM 1024
#define HDIM 1024
#define G4 4096
#define NREC 128

__device__ __forceinline__ float sigf(float x) {
  x = fminf(fmaxf(x, -30.f), 30.f);
  return 1.f / (1.f + __expf(-x));
}
__device__ __forceinline__ float tanh_(float x) {
  x = fminf(fmaxf(x, -15.f), 15.f);
  float e = __expf(2.f * x);
  return (e - 1.f) / (e + 1.f);
}
__device__ __forceinline__ f32x4 MFMA(bf8 a, bf8 b, f32x4 c) {
  return __builtin_amdgcn_mfma_f32_16x16x32_bf16(a, b, c, 0, 0, 0);
}
__device__ __forceinline__ f32x16 MFMA32(bf8 a, bf8 b, f32x16 c) {
  return __builtin_amdgcn_mfma_f32_32x32x16_bf16(a, b, c, 0, 0, 0);
}

// ---------------------------------------------------------------------------
// Weight transpose+convert via LDS tiles (plain [n][k] bf16 for BOTH Wx, Wh).
// ---------------------------------------------------------------------------
__global__ __launch_bounds__(256) void k_convw(
    const float* __restrict__ s0, const float* __restrict__ s1,
    const float* __restrict__ s2, const float* __restrict__ s3,
    const float* __restrict__ s4, const float* __restrict__ s5,
    const float* __restrict__ s6, const float* __restrict__ s7,
    __bf16* __restrict__ WxT, __bf16* __restrict__ WhT) {
  int z = blockIdx.z;
  const float* src = (z == 0) ? s0 : (z == 1) ? s1 : (z == 2) ? s2 :
                     (z == 3) ? s3 : (z == 4) ? s4 : (z == 5) ? s5 :
                     (z == 6) ? s6 : s7;
  __bf16* dst = (z < 4) ? WxT : WhT;
  int j0 = blockIdx.x * 64, k0 = blockIdx.y * 64;
  __shared__ float T[64][65];
  int tid = threadIdx.x;
#pragma unroll
  for (int i = 0; i < 16; ++i) {
    int idx = tid + i * 256;
    int kl = idx >> 6, jl = idx & 63;
    T[kl][jl] = src[(size_t)(k0 + kl) * 1024 + j0 + jl];
  }
  __syncthreads();
#pragma unroll
  for (int i = 0; i < 2; ++i) {
    int Gt = tid + i * 256;
    int nl = Gt >> 3, gq = Gt & 7;
    int n = (z & 3) * 1024 + j0 + nl;
    bf8 v;
#pragma unroll
    for (int e = 0; e < 8; ++e) v[e] = (__bf16)T[gq * 8 + e][nl];
    *(bf8*)&dst[(size_t)n * 1024 + k0 + gq * 8] = v;
  }
}

__global__ void k_bias(const float* __restrict__ b0, const float* __restrict__ b1,
                       const float* __restrict__ b2, const float* __restrict__ b3,
                       float* __restrict__ bias) {
  int i = blockIdx.x * 256 + threadIdx.x;
  if (i < G4) {
    const float* s = (i < 1024) ? b0 : (i < 2048) ? b1 : (i < 3072) ? b2 : b3;
    bias[i] = s[i & 1023];
  }
}

// ---------------------------------------------------------------------------
// Fused persistent kernel. grid = 256 x 512 threads.
//  blocks [0, nrec):    recurrence for chunk starting at t0 (Tc steps)
//  blocks [nrec, 256):  GEMM Xg_w = Xnext @ WxT^T + bias (next chunk's gates)
//
// Recurrence block bid: rh = bid&1 (rows rh*32..+32), hc0 = (bid>>1)*16.
// MFMA 32x32x16. Wave w: nc = w&1 (ncol tile of 32), kq = w>>1 (K quarter).
// Bf[16] x 4 VGPR = 64 VGPR register-resident (round-7-proven size).
// h staged COALESCED (u64 agent atomics) into XOR-swizzled LDS (round-7 path).
// Exchange: Gs[8 tiles][32 col][32 row] transposed b128 + direct scalar read.
// Sync (proven): per-block int flag, all-wave poll v >= t, end barrier + tid0.
// ---------------------------------------------------------------------------
__global__ __launch_bounds__(512, 1) void k_fused(
    const float* __restrict__ Xg_r, float* __restrict__ Xg_w,
    const __bf16* __restrict__ WhT, const __bf16* __restrict__ WxT,
    const float* __restrict__ Xnext, const float* __restrict__ bias,
    __bf16* __restrict__ hb0, __bf16* __restrict__ hb1,
    float* __restrict__ S, float* __restrict__ out,
    int* flags, int t0, int Tc, int nrec, int gM) {
  __shared__ char smem[65536];
  const int bid = blockIdx.x, tid = threadIdx.x;
  const int lane = tid & 63, w = tid >> 6;

  if (bid < nrec) {
    // =================== recurrence ===================
    bf8 (*Ls)[128] = (bf8(*)[128])smem;      // [32 rows][128 granules] = 64KB
    float* Gsf = (float*)smem;               // alias: Gs[8][32][32] f32 = 32KB
    const int nc = w & 1, kq = w >> 1;
    const int rh = bid & 1, hc0 = (bid >> 1) * 16;
    const int l31 = lane & 31, hi = lane >> 5;
    const int rowbase = rh * 32;

    // ---- Wh fragments (32x32x16 B): lane col = nc*32+l31, k = kq*256+s*16+hi*8
    bf8 Bf[16];
    {
      const int lc = nc * 32 + l31;
      const __bf16* wp = WhT + (size_t)((lc >> 4) * 1024 + hc0 + (lc & 15)) * 1024 +
                         kq * 256 + hi * 8;
#pragma unroll
      for (int s = 0; s < 16; ++s) Bf[s] = *(const bf8*)(wp + s * 16);
    }
#pragma unroll
    for (int i = 0; i < 16; ++i) {
      float4 tp = __builtin_bit_cast(float4, Bf[i]);
      asm volatile("" : "+v"(tp.x), "+v"(tp.y), "+v"(tp.z), "+v"(tp.w));
      Bf[i] = __builtin_bit_cast(bf8, tp);
    }

    // ---- gate-phase mapping: 1 (batch,col) per thread ----
    const int er = tid >> 4, ec = tid & 15;
    float sreg = 0.f;
    if (t0 > 0) sreg = S[(size_t)(rowbase + er) * 1024 + hc0 + ec];

    for (int lt = 0; lt < Tc; ++lt) {
      const int t = t0 + lt;

      // Xg prefetch (independent of h, overlaps poll)
      const float* xp = Xg_r + ((size_t)lt * 64 + rowbase + er) * G4 + hc0 + ec;
      float xa = xp[0], xi = xp[1024], xf = xp[2048], xo = xp[3072];

      if (t > 0) {
        if (lt > 0) {
          // poll same-rh producers: monotone >= (skew-tolerant, proven)
          int v;
          do {
            v = __hip_atomic_load(flags + (2 * lane + rh) * 32, __ATOMIC_RELAXED,
                                  __HIP_MEMORY_SCOPE_AGENT);
          } while (!__all(v >= t));
          asm volatile("" ::: "memory");   // no hoisting h-loads above poll
        }
        const __bf16* hp = ((t - 1) & 1) ? hb1 : hb0;

        // stage h[rowbase..+32)[0..1024) -> swizzled LDS, COALESCED loads
        union { u64 q[2]; bf8 v; } vv[8];
#pragma unroll
        for (int i = 0; i < 8; ++i) {
          int g = i * 512 + tid;
          const u64* sp = (const u64*)(hp + (size_t)(rowbase + (g >> 7)) * 1024 +
                                       (g & 127) * 8);
          vv[i].q[0] = __hip_atomic_load((u64*)sp, __ATOMIC_RELAXED,
                                         __HIP_MEMORY_SCOPE_AGENT);
          vv[i].q[1] = __hip_atomic_load((u64*)sp + 1, __ATOMIC_RELAXED,
                                         __HIP_MEMORY_SCOPE_AGENT);
        }
#pragma unroll
        for (int i = 0; i < 8; ++i) {
          int g = i * 512 + tid, r = g >> 7, cg = g & 127;
          Ls[r][cg ^ (r & 7)] = vv[i].v;
        }
        __syncthreads();   // b1: stage complete

        // MFMA 32x32x16: wave (nc,kq): 16 MFMAs, one C tile 32x32
        f32x16 acc = {};
#pragma unroll
        for (int s = 0; s < 16; ++s) {
          int c = (kq * 16 + s) * 2 + hi;
          bf8 af = Ls[l31][c ^ (l31 & 7)];
          acc = MFMA32(af, Bf[s], acc);
        }
        __syncthreads();   // b2: all A-reads done before Gs alias-write

        // transposed partial write: tile = nc*4+kq, [col 32][row-granule 8]
        {
          float* gt = Gsf + (nc * 4 + kq) * 1024 + l31 * 32;
#pragma unroll
          for (int q = 0; q < 4; ++q) {
            int rg = 2 * q + hi;
            f32x4 v4 = { acc[4 * q + 0], acc[4 * q + 1],
                         acc[4 * q + 2], acc[4 * q + 3] };
            *(f32x4*)(gt + ((rg ^ (l31 & 7)) << 2)) = v4;
          }
        }
        __syncthreads();   // b3: partials visible

        // direct gate read: 4 kq partials per gate, scalar b32
        {
          const int rg = er >> 2, e = er & 3;
#pragma unroll
          for (int g = 0; g < 4; ++g) {
            int lc2 = g * 16 + ec;
            int ncl = lc2 >> 5, col = lc2 & 31;
            const float* gp = Gsf + ncl * 4096 + col * 32 +
                              ((rg ^ (col & 7)) << 2) + e;
            float v = gp[0] + gp[1024] + gp[2048] + gp[3072];
            if (g == 0) xa += v;
            else if (g == 1) xi += v;
            else if (g == 2) xf += v;
            else xo += v;
          }
        }
      }

      // ---- gates + state update ----
      float av = tanh_(xa), iv = sigf(xi), fv = sigf(xf), ov = sigf(xo);
      sreg = av * iv + sreg * fv;
      float h0 = tanh_(sreg) * ov;

      out[((size_t)t * 64 + rowbase + er) * 1024 + hc0 + ec] = h0;

      float hnb = __shfl(h0, lane + 1);
      if ((ec & 1) == 0) {
        unsigned int pv =
            (unsigned int)__builtin_bit_cast(unsigned short, (__bf16)h0) |
            ((unsigned int)__builtin_bit_cast(unsigned short, (__bf16)hnb) << 16);
        __bf16* hn = (t & 1) ? hb1 : hb0;
        __hip_atomic_store(
            (unsigned int*)((char*)hn + ((size_t)(rowbase + er) * 1024 + hc0 + ec) * 2),
            pv, __ATOMIC_RELAXED, __HIP_MEMORY_SCOPE_AGENT);
      }

      __syncthreads();   // b4: h stores drained; Gs reads done (next stage safe)
      if (tid == 0)
        __hip_atomic_store(flags + bid * 32, t + 1, __ATOMIC_RELAXED,
                           __HIP_MEMORY_SCOPE_AGENT);
    }

    S[(size_t)(rowbase + er) * 1024 + hc0 + ec] = sreg;
    return;
  }

  // =================== worker GEMM (next chunk's Xg) ===================
  if (gM == 0) return;
  const int nw = gridDim.x - nrec;
  const int wid = bid - nrec;
  __bf16 (*As)[40] = (__bf16(*)[40])smem;
  __bf16 (*Bs)[40] = (__bf16(*)[40])(smem + 128 * 40 * 2);
  const int wr = (w >> 2) * 64, wc = (w & 3) * 32;
  const int sm = tid >> 2, sk = (tid & 3) * 8;
  const int gl15 = lane & 15, glq = lane >> 4;
  const int ntiles = (gM / 128) * (G4 / 128);

  for (int tile = wid; tile < ntiles; tile += nw) {
    const int m0 = (tile >> 5) * 128, n0 = (tile & 31) * 128;
    const float*  Ap = Xnext + (size_t)(m0 + sm) * 1024 + sk;
    const __bf16* Bp = WxT + (size_t)(n0 + sm) * 1024 + sk;
    f32x4 acc[4][2] = {};
    float4 ra0, ra1;
    bf8 rb;
    auto ld = [&](int kt) {
      ra0 = *(const float4*)(Ap + kt * 32);
      ra1 = *(const float4*)(Ap + kt * 32 + 4);
      rb = *(const bf8*)(Bp + kt * 32);
    };
    ld(0);
    for (int kt = 0; kt < 32; ++kt) {
      __syncthreads();
      bf8 va;
      va[0]=(__bf16)ra0.x; va[1]=(__bf16)ra0.y; va[2]=(__bf16)ra0.z; va[3]=(__bf16)ra0.w;
      va[4]=(__bf16)ra1.x; va[5]=(__bf16)ra1.y; va[6]=(__bf16)ra1.z; va[7]=(__bf16)ra1.w;
      *(bf8*)&As[sm][sk] = va;
      *(bf8*)&Bs[sm][sk] = rb;
      if (kt < 31) ld(kt + 1);
      __syncthreads();
      bf8 af[4], bv[2];
#pragma unroll
      for (int r = 0; r < 4; ++r) af[r] = *(const bf8*)&As[wr + r * 16 + gl15][glq * 8];
#pragma unroll
      for (int c = 0; c < 2; ++c) bv[c] = *(const bf8*)&Bs[wc + c * 16 + gl15][glq * 8];
#pragma unroll
      for (int r = 0; r < 4; ++r)
#pragma unroll
        for (int c = 0; c < 2; ++c)
          acc[r][c] = MFMA(af[r], bv[c], acc[r][c]);
    }
#pragma unroll
    for (int c = 0; c < 2; ++c) {
      int col = n0 + wc + c * 16 + gl15;
      float bc = bias[col];
#pragma unroll
      for (int r = 0; r < 4; ++r)
#pragma unroll
        for (int q = 0; q < 4; ++q)
          Xg_w[(size_t)(m0 + wr + r * 16 + glq * 4 + q) * G4 + col] = acc[r][c][q] + bc;
    }
    __syncthreads();
  }
}

// ---------------------------------------------------------------------------
extern "C" void kernel_launch(void* const* d_in, const int* in_sizes, int n_in,
                              void* d_out, int out_size, void* d_ws, size_t ws_size,
                              hipStream_t stream) {
  const float* X  = (const float*)d_in[0];
  const float* wa = (const float*)d_in[1];
  const float* wi = (const float*)d_in[2];
  const float* wf = (const float*)d_in[3];
  const float* wo = (const float*)d_in[4];
  const float* ha = (const float*)d_in[5];
  const float* hi = (const float*)d_in[6];
  const float* hf = (const float*)d_in[7];
  const float* ho = (const float*)d_in[8];
  const float* b0 = (const float*)d_in[9];
  const float* b1 = (const float*)d_in[10];
  const float* b2 = (const float*)d_in[11];
  const float* b3 = (const float*)d_in[12];
  float* out = (float*)d_out;
  char* ws = (char*)d_ws;

  size_t off = 0;
  auto alloc = [&](size_t bytes) {
    void* p = ws + off;
    off += (bytes + 255) & ~(size_t)255;
    return p;
  };
  __bf16* WxT = (__bf16*)alloc((size_t)G4 * IDIM * 2);
  __bf16* WhT = (__bf16*)alloc((size_t)G4 * HDIM * 2);
  float* bias = (float*)alloc(G4 * 4);
  float* S    = (float*)alloc((size_t)BBATCH * HDIM * 4);
  __bf16* hb0 = (__bf16*)alloc((size_t)BBATCH * HDIM * 2);
  __bf16* hb1 = (__bf16*)alloc((size_t)BBATCH * HDIM * 2);
  int* flags  = (int*)alloc(NREC * 32 * 4);
  size_t base = off;

  const size_t perXg = (size_t)BBATCH * G4 * 4;  // 1 MB per timestep
  int Tc = 64;
  while (Tc > 4 && base + 2 * (size_t)Tc * perXg > ws_size) Tc >>= 1;
  float* Xg0 = (float*)(ws + base);
  float* Xg1 = (float*)(ws + base + (size_t)Tc * perXg);
  int nchunks = TT / Tc;

  k_convw<<<dim3(16, 16, 8), dim3(256), 0, stream>>>(wa, wi, wf, wo, ha, hi, hf,
                                                     ho, WxT, WhT);
  k_bias<<<dim3(16), dim3(256), 0, stream>>>(b0, b1, b2, b3, bias);
  hipMemsetAsync(flags, 0, NREC * 32 * 4, stream);

  // prologue: all 256 blocks compute chunk 0's Xg
  k_fused<<<dim3(256), dim3(512), 0, stream>>>(
      nullptr, Xg0, WhT, WxT, X, bias, hb0, hb1, S, out, flags,
      0, 0, /*nrec=*/0, /*gM=*/Tc * BBATCH);

  for (int c = 0; c < nchunks; ++c) {
    float* xr = (c & 1) ? Xg1 : Xg0;
    float* xw = (c & 1) ? Xg0 : Xg1;
    int gM = (c + 1 < nchunks) ? Tc * BBATCH : 0;
    const float* Xn = X + (size_t)(c + 1) * Tc * BBATCH * IDIM;
    k_fused<<<dim3(256), dim3(512), 0, stream>>>(
        xr, xw, WhT, WxT, Xn, bias, hb0, hb1, S, out, flags,
        c * Tc, Tc, /*nrec=*/NREC, gM);
  }
}

// Round 12
// 2031.967 us; speedup vs baseline: 1.4983x; 1.0378x over previous
//
#include <hip/hip_runtime.h>
#include <hip/hip_bf16.h>

typedef __bf16 bf8 __attribute__((ext_vector_type(8)));   // 16 B
typedef float  f32x4  __attribute__((ext_vector_type(4)));
typedef float  f32x16 __attribute__((ext_vector_type(16)));
typedef unsigned long long u64;

#define TT 512
#define BBATCH 64
#define IDIM 1024
#define HDIM 1024
#define G4 4096
#define NREC 128

__device__ __forceinline__ float sigf(float x) {
  x = fminf(fmaxf(x, -30.f), 30.f);
  return 1.f / (1.f + __expf(-x));
}
__device__ __forceinline__ float tanh_(float x) {
  x = fminf(fmaxf(x, -15.f), 15.f);
  float e = __expf(2.f * x);
  return (e - 1.f) / (e + 1.f);
}
__device__ __forceinline__ f32x4 MFMA(bf8 a, bf8 b, f32x4 c) {
  return __builtin_amdgcn_mfma_f32_16x16x32_bf16(a, b, c, 0, 0, 0);
}
__device__ __forceinline__ f32x16 MFMA32(bf8 a, bf8 b, f32x16 c) {
  return __builtin_amdgcn_mfma_f32_32x32x16_bf16(a, b, c, 0, 0, 0);
}

// ---------------------------------------------------------------------------
// Weight transpose+convert via LDS tiles (plain [n][k] bf16 for BOTH Wx, Wh).
// ---------------------------------------------------------------------------
__global__ __launch_bounds__(256) void k_convw(
    const float* __restrict__ s0, const float* __restrict__ s1,
    const float* __restrict__ s2, const float* __restrict__ s3,
    const float* __restrict__ s4, const float* __restrict__ s5,
    const float* __restrict__ s6, const float* __restrict__ s7,
    __bf16* __restrict__ WxT, __bf16* __restrict__ WhT) {
  int z = blockIdx.z;
  const float* src = (z == 0) ? s0 : (z == 1) ? s1 : (z == 2) ? s2 :
                     (z == 3) ? s3 : (z == 4) ? s4 : (z == 5) ? s5 :
                     (z == 6) ? s6 : s7;
  __bf16* dst = (z < 4) ? WxT : WhT;
  int j0 = blockIdx.x * 64, k0 = blockIdx.y * 64;
  __shared__ float T[64][65];
  int tid = threadIdx.x;
#pragma unroll
  for (int i = 0; i < 16; ++i) {
    int idx = tid + i * 256;
    int kl = idx >> 6, jl = idx & 63;
    T[kl][jl] = src[(size_t)(k0 + kl) * 1024 + j0 + jl];
  }
  __syncthreads();
#pragma unroll
  for (int i = 0; i < 2; ++i) {
    int Gt = tid + i * 256;
    int nl = Gt >> 3, gq = Gt & 7;
    int n = (z & 3) * 1024 + j0 + nl;
    bf8 v;
#pragma unroll
    for (int e = 0; e < 8; ++e) v[e] = (__bf16)T[gq * 8 + e][nl];
    *(bf8*)&dst[(size_t)n * 1024 + k0 + gq * 8] = v;
  }
}

__global__ void k_bias(const float* __restrict__ b0, const float* __restrict__ b1,
                       const float* __restrict__ b2, const float* __restrict__ b3,
                       float* __restrict__ bias) {
  int i = blockIdx.x * 256 + threadIdx.x;
  if (i < G4) {
    const float* s = (i < 1024) ? b0 : (i < 2048) ? b1 : (i < 3072) ? b2 : b3;
    bias[i] = s[i & 1023];
  }
}

// ---------------------------------------------------------------------------
// Fused persistent kernel. grid = 256 x 512 threads.
//  blocks [0, nrec):    recurrence for chunk starting at t0 (Tc steps)
//  blocks [nrec, 256):  GEMM Xg_w = Xnext @ WxT^T + bias (next chunk's gates)
//
// h buffers use the MFMA A-FRAGMENT layout: hA[rh 2][gran 128][row 32][8 bf16]
// (element (row, k) at hA[rh][k>>3][row][k&7]).  Consumers load A-fragments
// as coalesced 512B u64-atomic wave-loads directly from LLC -- NO LDS stage.
// Wave w = ko (K-eighth of 128, dup-free). Bf[2 nc][8] = 64 VGPR resident.
// LDS: Gs[2 nc][8 ko][32 col][32 row] partials + 2-level reduce = 64KB EXACT.
// Sync (proven r4-r10): per-block int flag, full 64-flag monotone >= poll,
// double-buffered h, 3 barriers/step.
// ---------------------------------------------------------------------------
__global__ __launch_bounds__(512, 1) void k_fused(
    const float* __restrict__ Xg_r, float* __restrict__ Xg_w,
    const __bf16* __restrict__ WhT, const __bf16* __restrict__ WxT,
    const float* __restrict__ Xnext, const float* __restrict__ bias,
    __bf16* __restrict__ hb0, __bf16* __restrict__ hb1,
    float* __restrict__ S, float* __restrict__ out,
    int* flags, int t0, int Tc, int nrec, int gM) {
  __shared__ char smem[65536];                // Gs needs 2*8*32*32*4 = 64KB
  const int bid = blockIdx.x, tid = threadIdx.x;
  const int lane = tid & 63, w = tid >> 6;

  if (bid < nrec) {
    // =================== recurrence ===================
    float* Gsf = (float*)smem;               // Gs[2][8][32][32] f32 = 64KB
    const int ko = w;                        // K-eighth (128 k values)
    const int rh = bid & 1, hc0 = (bid >> 1) * 16;
    const int l31 = lane & 31, hi = lane >> 5;
    const int rowbase = rh * 32;

    // ---- Wh fragments: Bf[nc][s]: lane col lc = nc*32+l31 (gate = lc>>4,
    //      col16 = lc&15), k = ko*128 + s*16 + hi*8
    bf8 Bf[2][8];
#pragma unroll
    for (int nc = 0; nc < 2; ++nc) {
      const int lc = nc * 32 + l31;
      const __bf16* wp = WhT + (size_t)((lc >> 4) * 1024 + hc0 + (lc & 15)) * 1024 +
                         ko * 128 + hi * 8;
#pragma unroll
      for (int s = 0; s < 8; ++s) Bf[nc][s] = *(const bf8*)(wp + s * 16);
    }
#pragma unroll
    for (int nc = 0; nc < 2; ++nc)
#pragma unroll
      for (int i = 0; i < 8; ++i) {
        float4 tp = __builtin_bit_cast(float4, Bf[nc][i]);
        asm volatile("" : "+v"(tp.x), "+v"(tp.y), "+v"(tp.z), "+v"(tp.w));
        Bf[nc][i] = __builtin_bit_cast(bf8, tp);
      }

    // ---- gate-phase mapping: 1 (batch,col) per thread ----
    const int er = tid >> 4, ec = tid & 15;
    float sreg = 0.f;
    if (t0 > 0) sreg = S[(size_t)(rowbase + er) * 1024 + hc0 + ec];

    // producer h-store address (hA layout), packed u32 pairs
    const size_t hoff = ((size_t)((hc0 >> 3) + (ec >> 3)) * 32 + er) * 8 + (ec & 6);

    for (int lt = 0; lt < Tc; ++lt) {
      const int t = t0 + lt;

      // Xg prefetch (independent of h, overlaps poll)
      const float* xp = Xg_r + ((size_t)lt * 64 + rowbase + er) * G4 + hc0 + ec;
      float xa = xp[0], xi = xp[1024], xf = xp[2048], xo = xp[3072];

      if (t > 0) {
        if (lt > 0) {
          // poll same-rh producers: monotone >= (skew-tolerant, proven)
          int v;
          do {
            v = __hip_atomic_load(flags + (2 * lane + rh) * 32, __ATOMIC_RELAXED,
                                  __HIP_MEMORY_SCOPE_AGENT);
          } while (!__all(v >= t));
          asm volatile("" ::: "memory");   // no hoisting h-loads above poll
        }
        const __bf16* hA = (((t - 1) & 1) ? hb1 : hb0) + (size_t)rh * 32768;

        // A-frags: coalesced u64 atomic loads, granule c = ko*16 + s*2 + hi
        const u64* ap = (const u64*)(hA + ((size_t)(ko * 16 + hi) * 32 + l31) * 8);
        union { u64 q[2]; bf8 v; } a0, a1, a2, a3, a4, a5, a6, a7;
#define LD_A(AV, S) \
        AV.q[0] = __hip_atomic_load(ap + (S) * 128, __ATOMIC_RELAXED, \
                                    __HIP_MEMORY_SCOPE_AGENT); \
        AV.q[1] = __hip_atomic_load(ap + (S) * 128 + 1, __ATOMIC_RELAXED, \
                                    __HIP_MEMORY_SCOPE_AGENT);
        LD_A(a0, 0) LD_A(a1, 1) LD_A(a2, 2) LD_A(a3, 3)
        LD_A(a4, 4) LD_A(a5, 5) LD_A(a6, 6) LD_A(a7, 7)
#undef LD_A

        f32x16 acc0 = {}, acc1 = {};
#define MM(AV, S) \
        acc0 = MFMA32(AV.v, Bf[0][S], acc0); \
        acc1 = MFMA32(AV.v, Bf[1][S], acc1);
        MM(a0, 0) MM(a1, 1) MM(a2, 2) MM(a3, 3)
        MM(a4, 4) MM(a5, 5) MM(a6, 6) MM(a7, 7)
#undef MM

        // transposed partial write: Gs[nc][ko][col=l31][row], XOR-swizzled
#pragma unroll
        for (int q = 0; q < 4; ++q) {
          const int rg = 2 * q + hi;
          const int off = l31 * 32 + ((rg ^ (l31 & 7)) << 2);
          f32x4 v0 = { acc0[4 * q + 0], acc0[4 * q + 1],
                       acc0[4 * q + 2], acc0[4 * q + 3] };
          f32x4 v1 = { acc1[4 * q + 0], acc1[4 * q + 1],
                       acc1[4 * q + 2], acc1[4 * q + 3] };
          *(f32x4*)&Gsf[(0 * 8 + ko) * 1024 + off] = v0;
          *(f32x4*)&Gsf[(1 * 8 + ko) * 1024 + off] = v1;
        }
      }
      __syncthreads();   // b1: all partials visible

      if (t > 0) {
        // two-level reduce over ko: thread owns (tile tt, col, row-granule rg)
        const int tt = tid >> 8, col = (tid >> 3) & 31, rg = tid & 7;
        const int off = col * 32 + ((rg ^ (col & 7)) << 2);
        f32x4 sum = *(const f32x4*)&Gsf[tt * 8192 + off];
#pragma unroll
        for (int k2 = 1; k2 < 8; ++k2)
          sum += *(const f32x4*)&Gsf[tt * 8192 + k2 * 1024 + off];
        *(f32x4*)&Gsf[tt * 8192 + off] = sum;
      }
      __syncthreads();   // b2: sums visible

      if (t > 0) {
        const int rg2 = er >> 2, e = er & 3;
#pragma unroll
        for (int g = 0; g < 4; ++g) {
          const int lc2 = g * 16 + ec;
          const int tt2 = lc2 >> 5, col2 = lc2 & 31;
          float v = Gsf[tt2 * 8192 + col2 * 32 + ((rg2 ^ (col2 & 7)) << 2) + e];
          if (g == 0) xa += v;
          else if (g == 1) xi += v;
          else if (g == 2) xf += v;
          else xo += v;
        }
      }

      // ---- gates + state update ----
      float av = tanh_(xa), iv = sigf(xi), fv = sigf(xf), ov = sigf(xo);
      sreg = av * iv + sreg * fv;
      float h0 = tanh_(sreg) * ov;

      out[((size_t)t * 64 + rowbase + er) * 1024 + hc0 + ec] = h0;

      float hnb = __shfl(h0, lane + 1);
      if ((ec & 1) == 0) {
        unsigned int pv =
            (unsigned int)__builtin_bit_cast(unsigned short, (__bf16)h0) |
            ((unsigned int)__builtin_bit_cast(unsigned short, (__bf16)hnb) << 16);
        __bf16* hAn = ((t & 1) ? hb1 : hb0) + (size_t)rh * 32768;
        __hip_atomic_store((unsigned int*)((char*)hAn + hoff * 2), pv,
                           __ATOMIC_RELAXED, __HIP_MEMORY_SCOPE_AGENT);
      }

      __syncthreads();   // b3: all h stores drained; Gs reads done
      if (tid == 0)
        __hip_atomic_store(flags + bid * 32, t + 1, __ATOMIC_RELAXED,
                           __HIP_MEMORY_SCOPE_AGENT);
    }

    S[(size_t)(rowbase + er) * 1024 + hc0 + ec] = sreg;
    return;
  }

  // =================== worker GEMM (next chunk's Xg) ===================
  if (gM == 0) return;
  const int nw = gridDim.x - nrec;
  const int wid = bid - nrec;
  __bf16 (*As)[40] = (__bf16(*)[40])smem;                 // 10240 B
  __bf16 (*Bs)[40] = (__bf16(*)[40])(smem + 128 * 40 * 2);
  const int wr = (w >> 2) * 64, wc = (w & 3) * 32;
  const int sm = tid >> 2, sk = (tid & 3) * 8;
  const int gl15 = lane & 15, glq = lane >> 4;
  const int ntiles = (gM / 128) * (G4 / 128);

  for (int tile = wid; tile < ntiles; tile += nw) {
    const int m0 = (tile >> 5) * 128, n0 = (tile & 31) * 128;
    const float*  Ap = Xnext + (size_t)(m0 + sm) * 1024 + sk;
    const __bf16* Bp = WxT + (size_t)(n0 + sm) * 1024 + sk;
    f32x4 acc[4][2] = {};
    float4 ra0, ra1;
    bf8 rb;
    auto ld = [&](int kt) {
      ra0 = *(const float4*)(Ap + kt * 32);
      ra1 = *(const float4*)(Ap + kt * 32 + 4);
      rb = *(const bf8*)(Bp + kt * 32);
    };
    ld(0);
    for (int kt = 0; kt < 32; ++kt) {
      __syncthreads();
      bf8 va;
      va[0]=(__bf16)ra0.x; va[1]=(__bf16)ra0.y; va[2]=(__bf16)ra0.z; va[3]=(__bf16)ra0.w;
      va[4]=(__bf16)ra1.x; va[5]=(__bf16)ra1.y; va[6]=(__bf16)ra1.z; va[7]=(__bf16)ra1.w;
      *(bf8*)&As[sm][sk] = va;
      *(bf8*)&Bs[sm][sk] = rb;
      if (kt < 31) ld(kt + 1);
      __syncthreads();
      bf8 af[4], bv[2];
#pragma unroll
      for (int r = 0; r < 4; ++r) af[r] = *(const bf8*)&As[wr + r * 16 + gl15][glq * 8];
#pragma unroll
      for (int c = 0; c < 2; ++c) bv[c] = *(const bf8*)&Bs[wc + c * 16 + gl15][glq * 8];
#pragma unroll
      for (int r = 0; r < 4; ++r)
#pragma unroll
        for (int c = 0; c < 2; ++c)
          acc[r][c] = MFMA(af[r], bv[c], acc[r][c]);
    }
#pragma unroll
    for (int c = 0; c < 2; ++c) {
      int col = n0 + wc + c * 16 + gl15;
      float bc = bias[col];
#pragma unroll
      for (int r = 0; r < 4; ++r)
#pragma unroll
        for (int q = 0; q < 4; ++q)
          Xg_w[(size_t)(m0 + wr + r * 16 + glq * 4 + q) * G4 + col] = acc[r][c][q] + bc;
    }
    __syncthreads();
  }
}

// ---------------------------------------------------------------------------
extern "C" void kernel_launch(void* const* d_in, const int* in_sizes, int n_in,
                              void* d_out, int out_size, void* d_ws, size_t ws_size,
                              hipStream_t stream) {
  const float* X  = (const float*)d_in[0];
  const float* wa = (const float*)d_in[1];
  const float* wi = (const float*)d_in[2];
  const float* wf = (const float*)d_in[3];
  const float* wo = (const float*)d_in[4];
  const float* ha = (const float*)d_in[5];
  const float* hi = (const float*)d_in[6];
  const float* hf = (const float*)d_in[7];
  const float* ho = (const float*)d_in[8];
  const float* b0 = (const float*)d_in[9];
  const float* b1 = (const float*)d_in[10];
  const float* b2 = (const float*)d_in[11];
  const float* b3 = (const float*)d_in[12];
  float* out = (float*)d_out;
  char* ws = (char*)d_ws;

  size_t off = 0;
  auto alloc = [&](size_t bytes) {
    void* p = ws + off;
    off += (bytes + 255) & ~(size_t)255;
    return p;
  };
  __bf16* WxT = (__bf16*)alloc((size_t)G4 * IDIM * 2);
  __bf16* WhT = (__bf16*)alloc((size_t)G4 * HDIM * 2);
  float* bias = (float*)alloc(G4 * 4);
  float* S    = (float*)alloc((size_t)BBATCH * HDIM * 4);
  __bf16* hb0 = (__bf16*)alloc((size_t)BBATCH * HDIM * 2);
  __bf16* hb1 = (__bf16*)alloc((size_t)BBATCH * HDIM * 2);
  int* flags  = (int*)alloc(NREC * 32 * 4);
  size_t base = off;

  const size_t perXg = (size_t)BBATCH * G4 * 4;  // 1 MB per timestep
  int Tc = 64;
  while (Tc > 4 && base + 2 * (size_t)Tc * perXg > ws_size) Tc >>= 1;
  float* Xg0 = (float*)(ws + base);
  float* Xg1 = (float*)(ws + base + (size_t)Tc * perXg);
  int nchunks = TT / Tc;

  k_convw<<<dim3(16, 16, 8), dim3(256), 0, stream>>>(wa, wi, wf, wo, ha, hi, hf,
                                                     ho, WxT, WhT);
  k_bias<<<dim3(16), dim3(256), 0, stream>>>(b0, b1, b2, b3, bias);
  hipMemsetAsync(flags, 0, NREC * 32 * 4, stream);

  // prologue: all 256 blocks compute chunk 0's Xg
  k_fused<<<dim3(256), dim3(512), 0, stream>>>(
      nullptr, Xg0, WhT, WxT, X, bias, hb0, hb1, S, out, flags,
      0, 0, /*nrec=*/0, /*gM=*/Tc * BBATCH);

  for (int c = 0; c < nchunks; ++c) {
    float* xr = (c & 1) ? Xg1 : Xg0;
    float* xw = (c & 1) ? Xg0 : Xg1;
    int gM = (c + 1 < nchunks) ? Tc * BBATCH : 0;
    const float* Xn = X + (size_t)(c + 1) * Tc * BBATCH * IDIM;
    k_fused<<<dim3(256), dim3(512), 0, stream>>>(
        xr, xw, WhT, WxT, Xn, bias, hb0, hb1, S, out, flags,
        c * Tc, Tc, /*nrec=*/NREC, gM);
  }
}